// Round 1
// 1585.667 us; speedup vs baseline: 1.1995x; 1.1995x over previous
//
#include <hip/hip_runtime.h>

typedef _Float16 f16_t;
typedef _Float16 f16x8 __attribute__((ext_vector_type(8)));
typedef _Float16 f16x4 __attribute__((ext_vector_type(4)));
typedef _Float16 f16x2 __attribute__((ext_vector_type(2)));
typedef float    f32x4 __attribute__((ext_vector_type(4)));

#define LAYERS 12
#define HDIM   256
#define CDIM   256
#define BROWS  32     // batch rows per block

// packed-weight workspace layout (f16 elements)
#define W0P_OFF 0
#define WCP_OFF 8192
#define WRP_OFF 73728
#define WRP_SZ  65536
#define WFP_OFF 335872
#define LSTRIDE 532480
#define PACK_TOTAL (LAYERS * LSTRIDE)
#define CTX_BYTE ((size_t)PACK_TOTAL * 2)

// s_waitcnt immediate (gfx9 encoding): lgkmcnt==0, others free
#define WAIT_LGKM0  __builtin_amdgcn_s_waitcnt(0xC07F)

// ---------------------------------------------------------------------------
// Prepass: mask + cast + pack weights into MFMA B-fragment order.
// B-frag for 16x16x32: element (n = lane&15, k = quad*8+j) of tile (nt,kt)
// stored at ((nt*KT + kt)*64 + lane)*8 + j  -> one 16B chunk per lane,
// wave-contiguous: a single coalesced global_load_dwordx4 per (nt,kt) slice.
// ---------------------------------------------------------------------------
__global__ __launch_bounds__(256) void nsf_pack(
    const float* __restrict__ W0, const float* __restrict__ Wc,
    const float* __restrict__ Wr, const float* __restrict__ Wf,
    f16_t* __restrict__ wp)
{
    int e = blockIdx.x * 256 + threadIdx.x;
    if (e >= PACK_TOTAL) return;
    int l = e / LSTRIDE;
    int r = e - l * LSTRIDE;
    float v = 0.f;
    if (r < WCP_OFF) {                       // W0p: N=256, K=32 (padded from 16), masked m0
        int t = r >> 9, lane = (r >> 3) & 63, j = r & 7;
        int n = t * 16 + (lane & 15);
        int k = (lane >> 4) * 8 + j;
        if (k < 16 && (n % 15 + 1) >= (k + 1))
            v = W0[(l * HDIM + n) * 16 + k];
    } else if (r < WRP_OFF) {                // Wcp: N=256, K=256, no mask
        int q = r - WCP_OFF;
        int t = q >> 9, lane = (q >> 3) & 63, j = q & 7;
        int n = (t >> 3) * 16 + (lane & 15);
        int k = (t & 7) * 32 + (lane >> 4) * 8 + j;
        v = Wc[(l * HDIM + n) * CDIM + k];
    } else if (r < WFP_OFF) {                // Wrp[4]: N=256, K=256, masked mh
        int q = r - WRP_OFF;
        int rr = q >> 16; q &= 65535;
        int t = q >> 9, lane = (q >> 3) & 63, j = q & 7;
        int n = (t >> 3) * 16 + (lane & 15);
        int k = (t & 7) * 32 + (lane >> 4) * 8 + j;
        if ((n % 15) >= (k % 15))
            v = Wr[(((l * 2 + (rr >> 1)) * 2 + (rr & 1)) * HDIM + n) * HDIM + k];
    } else {                                 // Wfp: N=768 (16 feats x 48, padded from 47), masked mf
        int q = r - WFP_OFF;
        int t = q >> 9, lane = (q >> 3) & 63, j = q & 7;
        int np = (t >> 3) * 16 + (lane & 15);
        int k = (t & 7) * 32 + (lane >> 4) * 8 + j;
        int f = np / 48, jj = np % 48;
        if (jj < 47 && (f + 1) > (k % 15 + 1))
            v = Wf[(l * 752 + f * 47 + jj) * HDIM + k];
    }
    wp[e] = (f16_t)v;
}

__global__ __launch_bounds__(256) void nsf_ctx16(
    const float* __restrict__ ctx, f16_t* __restrict__ c16, int n4)
{
    int i = blockIdx.x * 256 + threadIdx.x;
    if (i >= n4) return;
    float4 v = reinterpret_cast<const float4*>(ctx)[i];
    f16x4 o = { (f16_t)v.x, (f16_t)v.y, (f16_t)v.z, (f16_t)v.w };
    reinterpret_cast<f16x4*>(c16)[i] = o;
}

// ---------------------------------------------------------------------------
__device__ __forceinline__ float splus(float x) {   // softplus, fast HW ops only
    return fmaxf(x, 0.f) + __logf(1.f + __expf(-fabsf(x)));
}
__device__ __forceinline__ float loF(unsigned u) {
    f16x2 h = __builtin_bit_cast(f16x2, u); return (float)h[0];
}
__device__ __forceinline__ float hiF(unsigned u) {
    f16x2 h = __builtin_bit_cast(f16x2, u); return (float)h[1];
}

// ---------------------------------------------------------------------------
// C = A(32x256, LDS) * W^T(256xNT*16), B streamed global->VGPR directly.
// Weight slabs are wave-private: no LDS round-trip needed. Packed layout
// makes each lane's f16x8 B-fragment one coalesced global_load_dwordx4.
// Fully unrolled: the compiler pipelines the 8*NT independent loads
// against the MFMAs with counted vmcnt waits.
// ---------------------------------------------------------------------------
template <int NT>
__device__ __forceinline__ void gemm256_reg(f32x4 (&acc)[2][NT],
                                            const f16_t (&A)[BROWS][264],
                                            const f16_t* __restrict__ gbase,
                                            int quad, int l16)
{
#pragma unroll
    for (int kt = 0; kt < 8; ++kt) {
        f16x8 b[NT];
#pragma unroll
        for (int ni = 0; ni < NT; ++ni)
            b[ni] = *reinterpret_cast<const f16x8*>(gbase + ni * 4096 + kt * 512);
        f16x8 a[2];
#pragma unroll
        for (int mi = 0; mi < 2; ++mi)
            a[mi] = *reinterpret_cast<const f16x8*>(&A[mi * 16 + l16][kt * 32 + quad * 8]);
#pragma unroll
        for (int ni = 0; ni < NT; ++ni)
#pragma unroll
            for (int mi = 0; mi < 2; ++mi)
                acc[mi][ni] = __builtin_amdgcn_mfma_f32_16x16x32_f16(a[mi], b[ni], acc[mi][ni], 0, 0, 0);
    }
}

template <bool RELU>
__device__ __forceinline__ void stage_c(const f32x4 (&acc)[2][4], f16_t (&A)[BROWS][264],
                                        int wave, int quad, int l16)
{
#pragma unroll
    for (int mi = 0; mi < 2; ++mi)
#pragma unroll
        for (int ni = 0; ni < 4; ++ni)
#pragma unroll
            for (int rr = 0; rr < 4; ++rr) {
                float v = acc[mi][ni][rr];
                if (RELU) v = fmaxf(v, 0.f);
                A[mi * 16 + quad * 4 + rr][wave * 64 + ni * 16 + l16] = (f16_t)v;
            }
}

// ---------------------------------------------------------------------------
// Persistent flow kernel, 32 batch rows/block. LDS 34.8 KB -> 4 blocks/CU,
// VGPR capped at 128 (launch_bounds 256,4) -> 4 waves/SIMD.
// Weights stream straight into VGPRs (no LDS write/read traffic for B).
// Gf+spline are fully wave-local (feature f = wave*4+chunk).
// ---------------------------------------------------------------------------
template <bool CTX16>
__global__ __launch_bounds__(256, 4)
void nsf_flow(
    const float* __restrict__ x_in, const float* __restrict__ ctx32,
    const f16_t* __restrict__ ctx16,
    const float* __restrict__ b0, const float* __restrict__ bc,
    const float* __restrict__ br, const float* __restrict__ bfb,
    const f16_t* __restrict__ wp,
    float* __restrict__ out, int B)
{
    __shared__ f16_t act[BROWS][264];          // 16896 B  A-operand (activations)
    __shared__ f16_t pldsw[4][32][50];         // 12800 B  per-wave spline params
    __shared__ f16_t xstage[BROWS][40];        //  2560 B  flipped-x A tile
    __shared__ float xbuf[BROWS][16];          //  2048 B  fp32 x state
    __shared__ float ldsum[32][4];             //   512 B  logdet partials

    const int tid  = threadIdx.x;
    const int wave = tid >> 6, lane = tid & 63;
    const int quad = lane >> 4, l16 = lane & 15;
    const int row0 = blockIdx.x * BROWS;

    for (int i = tid; i < BROWS * 16; i += 256)
        xbuf[i >> 4][i & 15] = x_in[(size_t)row0 * 16 + i];

    float ld_acc = 0.f;

#pragma unroll 1
    for (int l = 0; l < LAYERS; ++l) {
        const f16_t* wl = wp + (size_t)l * LSTRIDE;
        __syncthreads();   // prior layer fully consumed act/xbuf (incl. all splines)

        // spline inputs for this wave's features f=wave*4+c, row=lane (lanes<32)
        float xval_c[4];
        if (lane < 32) {
#pragma unroll
            for (int c = 0; c < 4; ++c) xval_c[c] = xbuf[lane][15 - (wave * 4 + c)];
        }

        // stage ctx -> act (f16)
        if (CTX16) {
#pragma unroll
            for (int it = 0; it < 4; ++it) {
                int j = it * 256 + tid;          // 1024 chunks of 16B
                int rr = j >> 5, cg = j & 31;
                f16x8 v = *reinterpret_cast<const f16x8*>(ctx16 + (size_t)(row0 + rr) * CDIM + cg * 8);
                *reinterpret_cast<f16x8*>(&act[rr][cg * 8]) = v;
            }
        } else {
            int rr = tid >> 3, cg = tid & 7;
            const float* cptr = ctx32 + (size_t)(row0 + rr) * CDIM + cg * 32;
#pragma unroll
            for (int it = 0; it < 8; ++it) {
                float4 v = *reinterpret_cast<const float4*>(cptr + it * 4);
                f16x4 w4 = { (f16_t)v.x, (f16_t)v.y, (f16_t)v.z, (f16_t)v.w };
                *reinterpret_cast<f16x4*>(&act[rr][cg * 32 + it * 4]) = w4;
            }
        }
        // stage flipped x (zero-padded K 16..31) -> xstage
        for (int i = tid; i < BROWS * 32; i += 256) {
            int rr = i >> 5, c = i & 31;
            float v = (c < 16) ? xbuf[rr][15 - c] : 0.f;
            xstage[rr][c] = (f16_t)v;
        }
        __syncthreads();

        // ---- h = xf @ (W0*m0)^T + ctx @ Wc^T + b0 + bc ----
        f32x4 hacc[2][4];
#pragma unroll
        for (int ni = 0; ni < 4; ++ni) {
            int n = wave * 64 + ni * 16 + l16;
            float bv = b0[l * HDIM + n] + bc[l * HDIM + n];
#pragma unroll
            for (int mi = 0; mi < 2; ++mi) hacc[mi][ni] = (f32x4){bv, bv, bv, bv};
        }
        {
            f16x8 a[2];
#pragma unroll
            for (int mi = 0; mi < 2; ++mi)
                a[mi] = *reinterpret_cast<const f16x8*>(&xstage[mi * 16 + l16][quad * 8]);
#pragma unroll
            for (int ni = 0; ni < 4; ++ni) {
                f16x8 b = *reinterpret_cast<const f16x8*>(wl + W0P_OFF + ((wave * 4 + ni) * 64 + lane) * 8);
#pragma unroll
                for (int mi = 0; mi < 2; ++mi)
                    hacc[mi][ni] = __builtin_amdgcn_mfma_f32_16x16x32_f16(a[mi], b, hacc[mi][ni], 0, 0, 0);
            }
        }
        gemm256_reg<4>(hacc, act, wl + WCP_OFF + (size_t)wave * 4 * 4096 + lane * 8, quad, l16);

        // ---- 2 residual blocks ----
#pragma unroll 1
        for (int blk = 0; blk < 2; ++blk) {
            __syncthreads();
            stage_c<true>(hacc, act, wave, quad, l16);
            __syncthreads();
            f32x4 tacc[2][4];
#pragma unroll
            for (int ni = 0; ni < 4; ++ni) {
                int n = wave * 64 + ni * 16 + l16;
                float bv = br[((l * 2 + blk) * 2 + 0) * HDIM + n];
#pragma unroll
                for (int mi = 0; mi < 2; ++mi) tacc[mi][ni] = (f32x4){bv, bv, bv, bv};
            }
            gemm256_reg<4>(tacc, act,
                wl + WRP_OFF + (size_t)(blk * 2) * WRP_SZ + (size_t)wave * 4 * 4096 + lane * 8, quad, l16);
            __syncthreads();
            stage_c<true>(tacc, act, wave, quad, l16);
            __syncthreads();
#pragma unroll
            for (int ni = 0; ni < 4; ++ni) {
                int n = wave * 64 + ni * 16 + l16;
                float bv = br[((l * 2 + blk) * 2 + 1) * HDIM + n];
#pragma unroll
                for (int mi = 0; mi < 2; ++mi) tacc[mi][ni] = (f32x4){bv, bv, bv, bv};
            }
            gemm256_reg<4>(tacc, act,
                wl + WRP_OFF + (size_t)(blk * 2 + 1) * WRP_SZ + (size_t)wave * 4 * 4096 + lane * 8, quad, l16);
#pragma unroll
            for (int mi = 0; mi < 2; ++mi)
#pragma unroll
                for (int ni = 0; ni < 4; ++ni)
                    hacc[mi][ni] += tacc[mi][ni];
        }

        // ---- stage final h (no relu) ----
        __syncthreads();
        stage_c<false>(hacc, act, wave, quad, l16);
        __syncthreads();

        // ---- Gf + spline: fully wave-local, barrier-free ----
        // wave w, chunk c -> feature f = w*4+c, Wf tiles 3f..3f+2
#pragma unroll 1
        for (int c = 0; c < 4; ++c) {
            const int f = wave * 4 + c;
            f32x4 pacc[2][3];
#pragma unroll
            for (int ni = 0; ni < 3; ++ni) {
                int jj = ni * 16 + l16;
                float bv = (jj < 47) ? bfb[l * 752 + f * 47 + jj] : 0.f;
#pragma unroll
                for (int mi = 0; mi < 2; ++mi) pacc[mi][ni] = (f32x4){bv, bv, bv, bv};
            }
            gemm256_reg<3>(pacc, act, wl + WFP_OFF + (size_t)(3 * f) * 4096 + lane * 8, quad, l16);

            // park p in this wave's private LDS (row = batch, col = jj)
#pragma unroll
            for (int mi = 0; mi < 2; ++mi)
#pragma unroll
                for (int ni = 0; ni < 3; ++ni)
#pragma unroll
                    for (int rr = 0; rr < 4; ++rr)
                        pldsw[wave][mi * 16 + quad * 4 + rr][ni * 16 + l16] = (f16_t)pacc[mi][ni][rr];
            WAIT_LGKM0;   // ds in-order per wave + drained: rows visible to all lanes

            // ---- RQ spline: lanes 0..31, row = lane, feature f ----
            if (lane < 32) {
                float xval = xval_c[c];
                const unsigned* pp = reinterpret_cast<const unsigned*>(&pldsw[wave][lane][0]);
                float uw[16], uh[16], ud[15];
#pragma unroll
                for (int j = 0; j < 8; ++j) {
                    unsigned w2 = pp[j], h2 = pp[8 + j];
                    uw[2 * j]     = loF(w2) * 0.0625f;
                    uw[2 * j + 1] = hiF(w2) * 0.0625f;
                    uh[2 * j]     = loF(h2) * 0.0625f;
                    uh[2 * j + 1] = hiF(h2) * 0.0625f;
                }
#pragma unroll
                for (int j = 0; j < 7; ++j) {
                    unsigned d2 = pp[16 + j];
                    ud[2 * j]     = loF(d2);
                    ud[2 * j + 1] = hiF(d2);
                }
                ud[14] = loF(pp[23]);

                float mw = uw[0], mh2 = uh[0];
#pragma unroll
                for (int j = 1; j < 16; ++j) { mw = fmaxf(mw, uw[j]); mh2 = fmaxf(mh2, uh[j]); }
                float sw = 0.f, sh = 0.f;
#pragma unroll
                for (int j = 0; j < 16; ++j) {
                    uw[j] = __expf(uw[j] - mw); sw += uw[j];
                    uh[j] = __expf(uh[j] - mh2); sh += uh[j];
                }
                float rw = 0.984f / sw, rh = 0.984f / sh;
                float xc = fminf(fmaxf(xval, -3.f), 3.f);
                float cumw = 0.f, cumh = 0.f, dprev = 1.f;
                float icw = -3.f, iwv = 1.f, ich = -3.f, ihv = 1.f, dk = 1.f, dk1 = 1.f;
#pragma unroll
                for (int j = 0; j < 16; ++j) {
                    float wj = fmaf(rw, uw[j], 0.001f);
                    float hj = fmaf(rh, uh[j], 0.001f);
                    float cwn = cumw + wj, chn = cumh + hj;
                    float left  = (j == 0)  ? -3.f : fmaf(6.f, cumw, -3.f);
                    float right = (j == 15) ?  3.f : fmaf(6.f, cwn, -3.f);
                    float hl    = (j == 0)  ? -3.f : fmaf(6.f, cumh, -3.f);
                    float hr    = (j == 15) ?  3.f : fmaf(6.f, chn, -3.f);
                    float dn    = (j == 15) ? 1.f : (0.001f + splus(ud[j]));
                    if (xc >= left) {
                        icw = left; iwv = right - left;
                        ich = hl;   ihv = hr - hl;
                        dk = dprev; dk1 = dn;
                    }
                    cumw = cwn; cumh = chn; dprev = dn;
                }
                float delta = ihv / iwv;
                float th = (xc - icw) / iwv;
                float omth = 1.f - th;
                float t1m = th * omth;
                float den = delta + (dk + dk1 - 2.f * delta) * t1m;
                float y = ich + ihv * (delta * th * th + dk * t1m) / den;
                float dnum = delta * delta * (dk1 * th * th + 2.f * delta * t1m + dk * omth * omth);
                float ldv = __logf(dnum) - 2.f * __logf(den);
                bool inside = (xval >= -3.f) && (xval <= 3.f);
                xbuf[lane][f] = inside ? y : xval;
                ld_acc += inside ? ldv : 0.f;
            }
        }
    }

    __syncthreads();
    for (int i = tid; i < BROWS * 16; i += 256)
        out[(size_t)row0 * 16 + i] = xbuf[i >> 4][i & 15];
    if (lane < 32) ldsum[lane][wave] = ld_acc;
    __syncthreads();
    if (tid < 32)
        out[(size_t)B * 16 + row0 + tid] =
            ldsum[tid][0] + ldsum[tid][1] + ldsum[tid][2] + ldsum[tid][3];
}

// ---------------------------------------------------------------------------
extern "C" void kernel_launch(void* const* d_in, const int* in_sizes, int n_in,
                              void* d_out, int out_size, void* d_ws, size_t ws_size,
                              hipStream_t stream)
{
    const float* x   = (const float*)d_in[0];
    const float* ctx = (const float*)d_in[1];
    const float* W0  = (const float*)d_in[2];
    const float* b0  = (const float*)d_in[3];
    const float* Wc  = (const float*)d_in[4];
    const float* bc  = (const float*)d_in[5];
    const float* Wr  = (const float*)d_in[6];
    const float* br  = (const float*)d_in[7];
    const float* Wf  = (const float*)d_in[8];
    const float* bfb = (const float*)d_in[9];
    int B = in_sizes[0] / 16;

    f16_t* wp  = (f16_t*)d_ws;                     // 12.78 MB packed f16 weights
    f16_t* c16 = (f16_t*)((char*)d_ws + CTX_BYTE); // 33.5 MB f16 context (optional)
    bool useCtx16 = ws_size >= CTX_BYTE + (size_t)B * CDIM * 2;

    nsf_pack<<<(PACK_TOTAL + 255) / 256, 256, 0, stream>>>(W0, Wc, Wr, Wf, wp);
    if (useCtx16) {
        int n4 = B * CDIM / 4;
        nsf_ctx16<<<(n4 + 255) / 256, 256, 0, stream>>>(ctx, c16, n4);
        nsf_flow<true><<<B / BROWS, 256, 0, stream>>>(x, ctx, c16, b0, bc, br, bfb, wp, (float*)d_out, B);
    } else {
        nsf_flow<false><<<B / BROWS, 256, 0, stream>>>(x, ctx, c16, b0, bc, br, bfb, wp, (float*)d_out, B);
    }
}